// Round 7
// baseline (290.403 us; speedup 1.0000x reference)
//
#include <hip/hip_runtime.h>

#define NN 4096
#define DD 512
#define EE 64
#define HH 8

typedef _Float16 f16;
typedef f16 f16x4 __attribute__((ext_vector_type(4)));
typedef f16 f16x8 __attribute__((ext_vector_type(8)));
typedef float f32x4 __attribute__((ext_vector_type(4)));
typedef float f32x16 __attribute__((ext_vector_type(16)));

// hardware exp2 (v_exp_f32). NOTE: __exp2f collides with glibc math.h macros.
__device__ __forceinline__ float hexp2(float x) { return __builtin_amdgcn_exp2f(x); }

// ---------------- fused prep: converts + weight transposes, 1 launch ----------------
__device__ void tile_transpose_cvt(const float* __restrict__ src, f16* __restrict__ dst,
                                   int R, int C, int bx, int by, int tid)
{
    __shared__ float t[32][33];
    const int tx = tid & 31, ty = tid >> 5;
    #pragma unroll
    for (int i = 0; i < 4; ++i) {
        int r = ty + i * 8;
        t[r][tx] = src[(size_t)(by + r) * C + bx + tx];
    }
    __syncthreads();
    #pragma unroll
    for (int i = 0; i < 4; ++i) {
        int c = ty + i * 8;
        dst[(size_t)(bx + c) * R + by + tx] = (f16)t[tx][c];
    }
}

// grid (256, 6): y=0 x->f16 (8 passes), y=1 ffn_w->f16, y=2..4 wq/wk/wv transpose, y=5 w_mh transpose
__global__ __launch_bounds__(256) void prep_kernel(
    const float* __restrict__ x, const float* __restrict__ ffn_w,
    const float* __restrict__ wq, const float* __restrict__ wk, const float* __restrict__ wv,
    const float* __restrict__ w_mh,
    f16* __restrict__ xh, f16* __restrict__ ffnT, f16* __restrict__ wqkvT, f16* __restrict__ wmhT)
{
    const int job = blockIdx.y;
    const int tid = threadIdx.x;
    if (job == 0) {
        size_t i = ((size_t)blockIdx.x * 256 + tid) * 4;
        const size_t step = (size_t)256 * 256 * 4;
        for (; i < (size_t)NN * DD; i += step) {
            float4 t = *(const float4*)(x + i);
            f16x4 h = { (f16)t.x, (f16)t.y, (f16)t.z, (f16)t.w };
            *(f16x4*)(xh + i) = h;
        }
    } else if (job == 1) {
        size_t i = ((size_t)blockIdx.x * 256 + tid) * 4;   // DD*DD = 256 blocks exactly
        float4 t = *(const float4*)(ffn_w + i);
        f16x4 h = { (f16)t.x, (f16)t.y, (f16)t.z, (f16)t.w };
        *(f16x4*)(ffnT + i) = h;
    } else if (job <= 4) {
        const float* src = (job == 2) ? wq : (job == 3) ? wk : wv;
        f16* dst = wqkvT + (size_t)(job - 2) * HH * EE * DD;
        const int z = blockIdx.x >> 5;        // head 0..7
        const int tile = blockIdx.x & 31;     // 2 (E) x 16 (D)
        tile_transpose_cvt(src + (size_t)z * DD * EE, dst + (size_t)z * DD * EE,
                           DD, EE, (tile & 1) * 32, (tile >> 1) * 32, tid);
    } else {
        const int tile = blockIdx.x;          // 16 x 16
        tile_transpose_cvt(w_mh, wmhT, DD, DD, (tile & 15) * 32, (tile >> 4) * 32, tid);
    }
}

// ---------------- QKV GEMM via MFMA: C[64n x 64col] tiles, K=512 ----------------
__global__ __launch_bounds__(256) void qkv_mfma_kernel(
    const f16* __restrict__ A, const f16* __restrict__ BT,
    f16* __restrict__ qh, f16* __restrict__ kh, f16* __restrict__ vTh)
{
    __shared__ f16 As[64][72];
    __shared__ f16 Bs[64][72];
    const int tid = threadIdx.x;
    const int n0 = blockIdx.x * 64;
    const int cb = blockIdx.y;
    const int sel = cb >> 3, h = cb & 7;
    const f16* Arow = A + (size_t)n0 * DD;
    const f16* Brow = BT + (size_t)cb * 64 * DD;

    const int lane = tid & 63, wave = tid >> 6;
    const int l16 = lane & 15, quad = lane >> 4;
    const int m0 = wave * 16;

    f32x4 acc[4];
    #pragma unroll
    for (int t = 0; t < 4; ++t) acc[t] = (f32x4){0.f, 0.f, 0.f, 0.f};

    for (int kt = 0; kt < DD; kt += 64) {
        __syncthreads();
        #pragma unroll
        for (int i = 0; i < 2; ++i) {
            int idx = tid + i * 256;
            int r = idx >> 3, c8 = (idx & 7) * 8;
            *(f16x8*)(&As[r][c8]) = *(const f16x8*)(Arow + (size_t)r * DD + kt + c8);
            *(f16x8*)(&Bs[r][c8]) = *(const f16x8*)(Brow + (size_t)r * DD + kt + c8);
        }
        __syncthreads();
        #pragma unroll
        for (int kk = 0; kk < 64; kk += 32) {
            f16x8 a = *(const f16x8*)(&As[m0 + l16][kk + quad * 8]);
            #pragma unroll
            for (int t = 0; t < 4; ++t) {
                f16x8 b = *(const f16x8*)(&Bs[t * 16 + l16][kk + quad * 8]);
                acc[t] = __builtin_amdgcn_mfma_f32_16x16x32_f16(a, b, acc[t], 0, 0, 0);
            }
        }
    }

    if (sel == 2) {
        #pragma unroll
        for (int t = 0; t < 4; ++t) {
            int e = t * 16 + l16;
            #pragma unroll
            for (int r = 0; r < 4; ++r)
                vTh[((size_t)h * EE + e) * NN + n0 + m0 + quad * 4 + r] = (f16)acc[t][r];
        }
    } else {
        f16* o = (sel == 0) ? qh : kh;
        // q: bake 1/sqrt(E) * log2(e) so attention can use raw v_exp_f32 (exp2)
        const float s = (sel == 0) ? 0.125f * 1.44269504088896f : 1.0f;
        #pragma unroll
        for (int r = 0; r < 4; ++r) {
            int row = n0 + m0 + quad * 4 + r;
            #pragma unroll
            for (int t = 0; t < 4; ++t)
                o[(size_t)h * NN * EE + (size_t)row * EE + t * 16 + l16] = (f16)(acc[t][r] * s);
        }
    }
}

// ---------------- Flash attention v4: 32x32x16 MFMA, key bit-swizzle, reg-only P ----------------
// wave = (kt2,qt2): 32 keys x 32 q-rows. S^T = K.Q^T with key k stored at LDS row
// swap(bits2,3)(k): C regs [0..7]/[8..15] of exp(S^T) are identity-mapped to the two
// PV B-fragments (C row = c+8a+16s+4u, swap23 -> key = c+4a+8u+16s). PV: O^T = V^T P^T.
// Cross-wave (kt2) O partials reduced once post-loop via LDS scratch.
#define BQ 64
#define BK 64
#define LK (BK + 12)   // 76 halfs: frag-read rows 38-bank-step -> 2-way (free)

__global__ __launch_bounds__(256) void attn_mfma_kernel(
    const f16* __restrict__ q, const f16* __restrict__ k,
    const f16* __restrict__ vT, float* __restrict__ Opart, float* __restrict__ lpart)
{
    __shared__ __align__(16) char smem[(size_t)(BK + EE) * LK * sizeof(f16)];
    f16 (*Ks)[LK]  = (f16(*)[LK])smem;
    f16 (*VsT)[LK] = (f16(*)[LK])(smem + (size_t)BK * LK * sizeof(f16));
    float* red = (float*)smem;   // 16 KB epilogue scratch (aliases Ks/VsT)

    const int tid = threadIdx.x;
    const int h = blockIdx.y;
    const int n0 = blockIdx.x * BQ;
    const int sp = blockIdx.z;
    const int nsp = gridDim.z;
    const int wave = tid >> 6;
    const int lane = tid & 63;
    const int l32 = lane & 31;
    const int u = lane >> 5;      // lane half
    const int qt2 = wave & 1;     // q-tile of 32
    const int kt2 = wave >> 1;    // key-tile of 32

    const f16* qh = q + (size_t)h * NN * EE;
    const f16* kh = k + (size_t)h * NN * EE;
    const f16* vh = vT + (size_t)h * NN * EE;  // [e][n]

    // Q B-fragments (loaded once): B[kd][q]: q=l32, kd = ks*16 + u*8 + j
    f16x8 qf[4];
    #pragma unroll
    for (int ks = 0; ks < 4; ++ks)
        qf[ks] = *(const f16x8*)(qh + (size_t)(n0 + qt2 * 32 + l32) * EE + ks * 16 + u * 8);

    float lp = 0.f;
    f32x16 O[2];
    #pragma unroll
    for (int i = 0; i < 16; ++i) { O[0][i] = 0.f; O[1][i] = 0.f; }

    const int span = NN / nsp;
    const int k_begin = sp * span;
    const int k_end = k_begin + span;

    const int srow = tid >> 3, sc8 = (tid & 7) * 8;
    const int srow2 = (tid + 256) >> 3, sc82 = ((tid + 256) & 7) * 8;
    // key -> LDS row: swap bits 2 and 3 (within each 32-key tile; bit5 preserved)
    #define KPERM2(kk_) (((kk_) & 0x33) | (((kk_) & 0x04) << 1) | (((kk_) & 0x08) >> 1))
    const int prow1 = KPERM2(srow), prow2 = KPERM2(srow2);

    // register prefetch of first tile
    f16x8 kr0 = *(const f16x8*)(kh + (size_t)(k_begin + srow) * EE + sc8);
    f16x8 kr1 = *(const f16x8*)(kh + (size_t)(k_begin + srow2) * EE + sc82);
    f16x8 vr0 = *(const f16x8*)(vh + (size_t)srow * NN + k_begin + sc8);
    f16x8 vr1 = *(const f16x8*)(vh + (size_t)srow2 * NN + k_begin + sc82);

    for (int kt = k_begin; kt < k_end; kt += BK) {
        __syncthreads();
        *(f16x8*)(&Ks[prow1][sc8]) = kr0;
        *(f16x8*)(&Ks[prow2][sc82]) = kr1;
        *(f16x8*)(&VsT[srow][sc8]) = vr0;
        *(f16x8*)(&VsT[srow2][sc82]) = vr1;
        __syncthreads();

        if (kt + BK < k_end) {   // prefetch next tile
            kr0 = *(const f16x8*)(kh + (size_t)(kt + BK + srow) * EE + sc8);
            kr1 = *(const f16x8*)(kh + (size_t)(kt + BK + srow2) * EE + sc82);
            vr0 = *(const f16x8*)(vh + (size_t)srow * NN + kt + BK + sc8);
            vr1 = *(const f16x8*)(vh + (size_t)srow2 * NN + kt + BK + sc82);
        }

        // S^T = K.Q^T over this wave's 32 keys: 4 ksteps of 16 in d
        f32x16 st;
        #pragma unroll
        for (int i = 0; i < 16; ++i) st[i] = 0.f;
        #pragma unroll
        for (int ks = 0; ks < 4; ++ks) {
            f16x8 a = *(const f16x8*)(&Ks[kt2 * 32 + l32][ks * 16 + u * 8]);
            st = __builtin_amdgcn_mfma_f32_32x32x16_f16(a, qf[ks], st, 0, 0, 0);
        }

        // p = exp2(s'); regs [0..7] -> PV kstep0 B-frag, [8..15] -> kstep1 (identity map)
        f16x8 bf0, bf1;
        #pragma unroll
        for (int r = 0; r < 8; ++r) {
            float p = hexp2(st[r]);
            lp += p;
            bf0[r] = (f16)p;
        }
        #pragma unroll
        for (int r = 0; r < 8; ++r) {
            float p = hexp2(st[8 + r]);
            lp += p;
            bf1[r] = (f16)p;
        }

        // O^T += V^T P^T over this wave's 32 keys
        #pragma unroll
        for (int et = 0; et < 2; ++et) {
            f16x8 a0 = *(const f16x8*)(&VsT[et * 32 + l32][kt2 * 32 + u * 8]);
            f16x8 a1 = *(const f16x8*)(&VsT[et * 32 + l32][kt2 * 32 + 16 + u * 8]);
            O[et] = __builtin_amdgcn_mfma_f32_32x32x16_f16(a0, bf0, O[et], 0, 0, 0);
            O[et] = __builtin_amdgcn_mfma_f32_32x32x16_f16(a1, bf1, O[et], 0, 0, 0);
        }
    }

    // ---- cross-wave O reduction (kt2 pair) via LDS scratch ----
    __syncthreads();
    if (kt2 == 1) {
        #pragma unroll
        for (int et = 0; et < 2; ++et)
            #pragma unroll
            for (int r = 0; r < 16; ++r)
                red[((qt2 * 2 + et) * 16 + r) * 64 + lane] = O[et][r];
    }
    __syncthreads();

    // l row-sums: combine lane halves; lanes 0..31 hold q = qt2*32 + lane (per kt2 slice)
    lp += __shfl_xor(lp, 32);
    if (lane < 32)
        lpart[((size_t)sp * 2 + kt2) * HH * NN + (size_t)h * NN + n0 + qt2 * 32 + lane] = lp;

    if (kt2 == 0) {
        #pragma unroll
        for (int et = 0; et < 2; ++et)
            #pragma unroll
            for (int r = 0; r < 16; ++r)
                O[et][r] += red[((qt2 * 2 + et) * 16 + r) * 64 + lane];
        // write: O^T[e][q] -> Opart[sp][n=q][h*64+e]; e = et*32 + 8g + 4u + c
        const int row = n0 + qt2 * 32 + l32;
        float* obase = Opart + ((size_t)sp * NN + row) * DD + h * EE;
        #pragma unroll
        for (int et = 0; et < 2; ++et)
            #pragma unroll
            for (int g = 0; g < 4; ++g) {
                f32x4 v = { O[et][g * 4 + 0], O[et][g * 4 + 1], O[et][g * 4 + 2], O[et][g * 4 + 3] };
                *(f32x4*)(obase + et * 32 + 8 * g + 4 * u) = v;
            }
    }
}

// ---------------- combine K-split partials: zh = sum(O_s)/sum(l_s), f16 out ----------------
__global__ __launch_bounds__(256) void attn_combine_kernel(
    const float* __restrict__ Opart, const float* __restrict__ lpart, f16* __restrict__ zh, int nsp)
{
    const size_t idx = ((size_t)blockIdx.x * 256 + threadIdx.x) * 8;
    const int n = (int)(idx >> 9);
    const int h = (int)((idx & 511) >> 6);
    float l = 0.f;
    for (int s = 0; s < 2 * nsp; ++s) l += lpart[(size_t)s * HH * NN + (size_t)h * NN + n];
    const float inv = 1.f / l;
    f32x4 a0 = {0.f,0.f,0.f,0.f}, a1 = {0.f,0.f,0.f,0.f};
    for (int s = 0; s < nsp; ++s) {
        a0 += *(const f32x4*)(Opart + (size_t)s * NN * DD + idx);
        a1 += *(const f32x4*)(Opart + (size_t)s * NN * DD + idx + 4);
    }
    f16x8 o;
    #pragma unroll
    for (int i = 0; i < 4; ++i) {
        o[i]     = (f16)(a0[i] * inv);
        o[i + 4] = (f16)(a1[i] * inv);
    }
    *(f16x8*)(zh + idx) = o;
}

// ---------------- GEMM via MFMA + bias/residual epilogue, fp32 out ----------------
__global__ __launch_bounds__(256) void gemm_mfma_kernel(
    const f16* __restrict__ A, const f16* __restrict__ BT,
    const float* __restrict__ bias, const float* __restrict__ resid32,
    const f16* __restrict__ resid16, float* __restrict__ out)
{
    __shared__ f16 As[64][72];
    __shared__ f16 Bs[64][72];
    const int tid = threadIdx.x;
    const int n0 = blockIdx.x * 64;
    const int j0 = blockIdx.y * 64;
    const f16* Arow = A + (size_t)n0 * DD;
    const f16* Brow = BT + (size_t)j0 * DD;

    const int lane = tid & 63, wave = tid >> 6;
    const int l16 = lane & 15, quad = lane >> 4;
    const int m0 = wave * 16;

    f32x4 acc[4];
    #pragma unroll
    for (int t = 0; t < 4; ++t) acc[t] = (f32x4){0.f, 0.f, 0.f, 0.f};

    for (int kt = 0; kt < DD; kt += 64) {
        __syncthreads();
        #pragma unroll
        for (int i = 0; i < 2; ++i) {
            int idx = tid + i * 256;
            int r = idx >> 3, c8 = (idx & 7) * 8;
            *(f16x8*)(&As[r][c8]) = *(const f16x8*)(Arow + (size_t)r * DD + kt + c8);
            *(f16x8*)(&Bs[r][c8]) = *(const f16x8*)(Brow + (size_t)r * DD + kt + c8);
        }
        __syncthreads();
        #pragma unroll
        for (int kk = 0; kk < 64; kk += 32) {
            f16x8 a = *(const f16x8*)(&As[m0 + l16][kk + quad * 8]);
            #pragma unroll
            for (int t = 0; t < 4; ++t) {
                f16x8 b = *(const f16x8*)(&Bs[t * 16 + l16][kk + quad * 8]);
                acc[t] = __builtin_amdgcn_mfma_f32_16x16x32_f16(a, b, acc[t], 0, 0, 0);
            }
        }
    }

    #pragma unroll
    for (int r = 0; r < 4; ++r) {
        int row = n0 + m0 + quad * 4 + r;
        #pragma unroll
        for (int t = 0; t < 4; ++t) {
            int col = j0 + t * 16 + l16;
            float v = acc[t][r];
            if (bias)    v += bias[col];
            if (resid32) v += resid32[(size_t)row * DD + col];
            if (resid16) v += (float)resid16[(size_t)row * DD + col];
            out[(size_t)row * DD + col] = v;
        }
    }
}

// ---------------- row LayerNorm: y fp32 [N][512] -> f16 and/or fp32 out ----------------
__global__ __launch_bounds__(256) void ln_kernel(
    const float* __restrict__ y, const float* __restrict__ g, const float* __restrict__ b,
    f16* __restrict__ oh, float* __restrict__ of)
{
    const int lane = threadIdx.x & 63, wave = threadIdx.x >> 6;
    const int row = blockIdx.x * 4 + wave;
    const float* yr = y + (size_t)row * DD;
    f32x4 v0 = *(const f32x4*)(yr + lane * 4);
    f32x4 v1 = *(const f32x4*)(yr + 256 + lane * 4);
    float s = (v0[0] + v0[1]) + (v0[2] + v0[3]) + (v1[0] + v1[1]) + (v1[2] + v1[3]);
    float q = (v0[0]*v0[0] + v0[1]*v0[1]) + (v0[2]*v0[2] + v0[3]*v0[3])
            + (v1[0]*v1[0] + v1[1]*v1[1]) + (v1[2]*v1[2] + v1[3]*v1[3]);
    #pragma unroll
    for (int o = 1; o < 64; o <<= 1) { s += __shfl_xor(s, o); q += __shfl_xor(q, o); }
    float mean = s * (1.f / DD);
    float var = q * (1.f / DD) - mean * mean;
    float inv = rsqrtf(var + 1e-5f);

    f32x4 g0 = *(const f32x4*)(g + lane * 4);
    f32x4 g1 = *(const f32x4*)(g + 256 + lane * 4);
    f32x4 b0 = *(const f32x4*)(b + lane * 4);
    f32x4 b1 = *(const f32x4*)(b + 256 + lane * 4);
    f32x4 o0, o1;
    #pragma unroll
    for (int i = 0; i < 4; ++i) {
        o0[i] = (v0[i] - mean) * inv * g0[i] + b0[i];
        o1[i] = (v1[i] - mean) * inv * g1[i] + b1[i];
    }
    if (oh) {
        f16x4 h0 = { (f16)o0[0], (f16)o0[1], (f16)o0[2], (f16)o0[3] };
        f16x4 h1 = { (f16)o1[0], (f16)o1[1], (f16)o1[2], (f16)o1[3] };
        *(f16x4*)(oh + (size_t)row * DD + lane * 4) = h0;
        *(f16x4*)(oh + (size_t)row * DD + 256 + lane * 4) = h1;
    }
    if (of) {
        *(f32x4*)(of + (size_t)row * DD + lane * 4) = o0;
        *(f32x4*)(of + (size_t)row * DD + 256 + lane * 4) = o1;
    }
}

extern "C" void kernel_launch(void* const* d_in, const int* in_sizes, int n_in,
                              void* d_out, int out_size, void* d_ws, size_t ws_size,
                              hipStream_t stream) {
    const float* x     = (const float*)d_in[0];
    const float* wq    = (const float*)d_in[1];
    const float* wk    = (const float*)d_in[2];
    const float* wv    = (const float*)d_in[3];
    const float* w_mh  = (const float*)d_in[4];
    const float* ln1_g = (const float*)d_in[5];
    const float* ln1_b = (const float*)d_in[6];
    const float* ffn_w = (const float*)d_in[7];
    const float* ffn_b = (const float*)d_in[8];
    const float* ln2_g = (const float*)d_in[9];
    const float* ln2_b = (const float*)d_in[10];
    float* out = (float*)d_out;

    // pool of f16 buffers that live across phases
    const size_t poolHalfs = (size_t)3 * HH * EE * DD + 2 * (size_t)DD * DD
                           + 3 * (size_t)HH * NN * EE + 2 * (size_t)NN * DD;
    // pick K-split count by available workspace (deterministic per session)
    int SP = 2;
    {
        size_t need4 = ((size_t)4 * NN * DD + 8 * HH * NN) * 4 + poolHalfs * 2 + 1024;
        size_t need3 = ((size_t)3 * NN * DD + 6 * HH * NN) * 4 + poolHalfs * 2 + 1024;
        if (ws_size >= need4) SP = 4; else if (ws_size >= need3) SP = 3;
    }

    // region A (aliased): xh (pre-attn) / Opart+lpart (attn) / y (post-combine)
    char* base = (char*)d_ws;
    float* Opart = (float*)base;                              // SP*NN*DD f32
    float* lpart = Opart + (size_t)SP * NN * DD;              // 2*SP*HH*NN f32
    f16* xh   = (f16*)base;                                   // alias (pre-attention)
    float* y  = (float*)base;                                 // alias (post-combine)
    size_t regionA = ((size_t)SP * NN * DD + (size_t)2 * SP * HH * NN) * sizeof(float);
    regionA = (regionA + 255) & ~(size_t)255;
    f16* p = (f16*)(base + regionA);
    f16* wqkvT  = p; p += (size_t)3 * HH * EE * DD;           // [sel][h][e][d]
    f16* wmhT   = p; p += (size_t)DD * DD;                    // [j][k]
    f16* ffnT   = p; p += (size_t)DD * DD;                    // [j][k]
    f16* qh     = p; p += (size_t)HH * NN * EE;               // [h][n][e], scale baked
    f16* kh     = p; p += (size_t)HH * NN * EE;               // [h][n][e]
    f16* vTh    = p; p += (size_t)HH * NN * EE;               // [h][e][n]
    f16* zh     = p; p += (size_t)NN * DD;                    // [n][h*e]
    f16* nzh    = p; p += (size_t)NN * DD;                    // LN1 out

    // prep (single launch)
    prep_kernel<<<dim3(256, 6), 256, 0, stream>>>(x, ffn_w, wq, wk, wv, w_mh,
                                                  xh, ffnT, wqkvT, wmhT);

    // main chain
    qkv_mfma_kernel<<<dim3(NN / 64, 24), 256, 0, stream>>>(xh, wqkvT, qh, kh, vTh);
    attn_mfma_kernel<<<dim3(NN / BQ, HH, SP), 256, 0, stream>>>(qh, kh, vTh, Opart, lpart);
    attn_combine_kernel<<<dim3(NN * DD / 2048), 256, 0, stream>>>(Opart, lpart, zh, SP);
    gemm_mfma_kernel<<<dim3(NN / 64, DD / 64), 256, 0, stream>>>(zh, wmhT, nullptr, x, nullptr, y);
    ln_kernel<<<dim3(NN / 4), 256, 0, stream>>>(y, ln1_g, ln1_b, nzh, nullptr);
    gemm_mfma_kernel<<<dim3(NN / 64, DD / 64), 256, 0, stream>>>(nzh, ffnT, ffn_b, nullptr, nzh, y);
    ln_kernel<<<dim3(NN / 4), 256, 0, stream>>>(y, ln2_g, ln2_b, nullptr, out);
}

// Round 8
// 186.487 us; speedup vs baseline: 1.5572x; 1.5572x over previous
//
#include <hip/hip_runtime.h>

#define NN 4096
#define DD 512
#define EE 64
#define HH 8

typedef _Float16 f16;
typedef f16 f16x4 __attribute__((ext_vector_type(4)));
typedef f16 f16x8 __attribute__((ext_vector_type(8)));
typedef float f32x4 __attribute__((ext_vector_type(4)));

// hardware exp2 (v_exp_f32). NOTE: __exp2f collides with glibc math.h macros.
__device__ __forceinline__ float hexp2(float x) { return __builtin_amdgcn_exp2f(x); }

// ---------------- fused prep: converts + weight transposes, 1 launch ----------------
__device__ void tile_transpose_cvt(const float* __restrict__ src, f16* __restrict__ dst,
                                   int R, int C, int bx, int by, int tid)
{
    __shared__ float t[32][33];
    const int tx = tid & 31, ty = tid >> 5;
    #pragma unroll
    for (int i = 0; i < 4; ++i) {
        int r = ty + i * 8;
        t[r][tx] = src[(size_t)(by + r) * C + bx + tx];
    }
    __syncthreads();
    #pragma unroll
    for (int i = 0; i < 4; ++i) {
        int c = ty + i * 8;
        dst[(size_t)(bx + c) * R + by + tx] = (f16)t[tx][c];
    }
}

// grid (256, 6): y=0 x->f16 (8 passes), y=1 ffn_w->f16, y=2..4 wq/wk/wv transpose, y=5 w_mh transpose
__global__ __launch_bounds__(256) void prep_kernel(
    const float* __restrict__ x, const float* __restrict__ ffn_w,
    const float* __restrict__ wq, const float* __restrict__ wk, const float* __restrict__ wv,
    const float* __restrict__ w_mh,
    f16* __restrict__ xh, f16* __restrict__ ffnT, f16* __restrict__ wqkvT, f16* __restrict__ wmhT)
{
    const int job = blockIdx.y;
    const int tid = threadIdx.x;
    if (job == 0) {
        size_t i = ((size_t)blockIdx.x * 256 + tid) * 4;
        const size_t step = (size_t)256 * 256 * 4;
        for (; i < (size_t)NN * DD; i += step) {
            float4 t = *(const float4*)(x + i);
            f16x4 h = { (f16)t.x, (f16)t.y, (f16)t.z, (f16)t.w };
            *(f16x4*)(xh + i) = h;
        }
    } else if (job == 1) {
        size_t i = ((size_t)blockIdx.x * 256 + tid) * 4;   // DD*DD = 256 blocks exactly
        float4 t = *(const float4*)(ffn_w + i);
        f16x4 h = { (f16)t.x, (f16)t.y, (f16)t.z, (f16)t.w };
        *(f16x4*)(ffnT + i) = h;
    } else if (job <= 4) {
        const float* src = (job == 2) ? wq : (job == 3) ? wk : wv;
        f16* dst = wqkvT + (size_t)(job - 2) * HH * EE * DD;
        const int z = blockIdx.x >> 5;        // head 0..7
        const int tile = blockIdx.x & 31;     // 2 (E) x 16 (D)
        tile_transpose_cvt(src + (size_t)z * DD * EE, dst + (size_t)z * DD * EE,
                           DD, EE, (tile & 1) * 32, (tile >> 1) * 32, tid);
    } else {
        const int tile = blockIdx.x;          // 16 x 16
        tile_transpose_cvt(w_mh, wmhT, DD, DD, (tile & 15) * 32, (tile >> 4) * 32, tid);
    }
}

// ---------------- QKV GEMM via MFMA: C[64n x 64col] tiles, K=512 ----------------
__global__ __launch_bounds__(256) void qkv_mfma_kernel(
    const f16* __restrict__ A, const f16* __restrict__ BT,
    f16* __restrict__ qh, f16* __restrict__ kh, f16* __restrict__ vTh)
{
    __shared__ f16 As[64][72];
    __shared__ f16 Bs[64][72];
    const int tid = threadIdx.x;
    const int n0 = blockIdx.x * 64;
    const int cb = blockIdx.y;
    const int sel = cb >> 3, h = cb & 7;
    const f16* Arow = A + (size_t)n0 * DD;
    const f16* Brow = BT + (size_t)cb * 64 * DD;

    const int lane = tid & 63, wave = tid >> 6;
    const int l16 = lane & 15, quad = lane >> 4;
    const int m0 = wave * 16;

    f32x4 acc[4];
    #pragma unroll
    for (int t = 0; t < 4; ++t) acc[t] = (f32x4){0.f, 0.f, 0.f, 0.f};

    for (int kt = 0; kt < DD; kt += 64) {
        __syncthreads();
        #pragma unroll
        for (int i = 0; i < 2; ++i) {
            int idx = tid + i * 256;
            int r = idx >> 3, c8 = (idx & 7) * 8;
            *(f16x8*)(&As[r][c8]) = *(const f16x8*)(Arow + (size_t)r * DD + kt + c8);
            *(f16x8*)(&Bs[r][c8]) = *(const f16x8*)(Brow + (size_t)r * DD + kt + c8);
        }
        __syncthreads();
        #pragma unroll
        for (int kk = 0; kk < 64; kk += 32) {
            f16x8 a = *(const f16x8*)(&As[m0 + l16][kk + quad * 8]);
            #pragma unroll
            for (int t = 0; t < 4; ++t) {
                f16x8 b = *(const f16x8*)(&Bs[t * 16 + l16][kk + quad * 8]);
                acc[t] = __builtin_amdgcn_mfma_f32_16x16x32_f16(a, b, acc[t], 0, 0, 0);
            }
        }
    }

    if (sel == 2) {
        #pragma unroll
        for (int t = 0; t < 4; ++t) {
            int e = t * 16 + l16;
            #pragma unroll
            for (int r = 0; r < 4; ++r)
                vTh[((size_t)h * EE + e) * NN + n0 + m0 + quad * 4 + r] = (f16)acc[t][r];
        }
    } else {
        f16* o = (sel == 0) ? qh : kh;
        // q: bake 1/sqrt(E) * log2(e) so attention can use raw v_exp_f32 (exp2)
        const float s = (sel == 0) ? 0.125f * 1.44269504088896f : 1.0f;
        #pragma unroll
        for (int r = 0; r < 4; ++r) {
            int row = n0 + m0 + quad * 4 + r;
            #pragma unroll
            for (int t = 0; t < 4; ++t)
                o[(size_t)h * NN * EE + (size_t)row * EE + t * 16 + l16] = (f16)(acc[t][r] * s);
        }
    }
}

// ---------------- Flash attention v5: v3 structure (16x16 MFMA, key-swizzle, reg-only P)
// + BQ=128: each wave owns TWO 16-row q-strips, reusing every K/V LDS fragment read
// for 2 MFMAs (halves LDS-read per FLOP — the structural cap identified in r6).
#define BQ 128
#define BK 64
#define LK (BK + 12)   // 76 halfs: frag-read row bank-step 6 mod 32 -> conflict-free

__global__ __launch_bounds__(256) void attn_mfma_kernel(
    const f16* __restrict__ q, const f16* __restrict__ k,
    const f16* __restrict__ vT, float* __restrict__ Opart, float* __restrict__ lpart)
{
    __shared__ f16 Ks[BK][LK];    // permuted key rows
    __shared__ f16 VsT[EE][LK];   // [e][key]

    const int tid = threadIdx.x;
    const int h = blockIdx.y;
    const int n0 = blockIdx.x * BQ;
    const int sp = blockIdx.z;
    const int nsp = gridDim.z;
    const int wave = tid >> 6;
    const int lane = tid & 63;
    const int l16 = lane & 15;
    const int quad = lane >> 4;
    const int m0 = wave * 16;

    const f16* qh = q + (size_t)h * NN * EE;
    const f16* kh = k + (size_t)h * NN * EE;
    const f16* vh = vT + (size_t)h * NN * EE;  // [e][n]

    // Q B-fragments for both strips (loaded once from global)
    f16x8 qf[2][2];
    #pragma unroll
    for (int s = 0; s < 2; ++s) {
        const f16* qb = qh + (size_t)(n0 + s * 64 + m0 + l16) * EE;
        qf[s][0] = *(const f16x8*)(qb + quad * 8);
        qf[s][1] = *(const f16x8*)(qb + 32 + quad * 8);
    }

    float lp[2] = {0.f, 0.f};
    f32x4 O[2][4];
    #pragma unroll
    for (int s = 0; s < 2; ++s)
        #pragma unroll
        for (int t = 0; t < 4; ++t) O[s][t] = (f32x4){0.f, 0.f, 0.f, 0.f};

    const int span = NN / nsp;
    const int k_begin = sp * span;
    const int k_end = k_begin + span;

    const int srow = tid >> 3, sc8 = (tid & 7) * 8;
    const int srow2 = (tid + 256) >> 3, sc82 = ((tid + 256) & 7) * 8;
    // key -> permuted LDS row: bits T,q,u,c -> T,u,q,c (verified r6)
    #define KPERM(kk_) (((kk_) & 0x23) | (((kk_) & 0x04) << 2) | (((kk_) & 0x18) >> 1))
    const int prow1 = KPERM(srow), prow2 = KPERM(srow2);

    // register prefetch of first tile
    f16x8 kr0 = *(const f16x8*)(kh + (size_t)(k_begin + srow) * EE + sc8);
    f16x8 kr1 = *(const f16x8*)(kh + (size_t)(k_begin + srow2) * EE + sc82);
    f16x8 vr0 = *(const f16x8*)(vh + (size_t)srow * NN + k_begin + sc8);
    f16x8 vr1 = *(const f16x8*)(vh + (size_t)srow2 * NN + k_begin + sc82);

    for (int kt = k_begin; kt < k_end; kt += BK) {
        __syncthreads();
        *(f16x8*)(&Ks[prow1][sc8]) = kr0;
        *(f16x8*)(&Ks[prow2][sc82]) = kr1;
        *(f16x8*)(&VsT[srow][sc8]) = vr0;
        *(f16x8*)(&VsT[srow2][sc82]) = vr1;
        __syncthreads();

        if (kt + BK < k_end) {   // prefetch next tile
            kr0 = *(const f16x8*)(kh + (size_t)(kt + BK + srow) * EE + sc8);
            kr1 = *(const f16x8*)(kh + (size_t)(kt + BK + srow2) * EE + sc82);
            vr0 = *(const f16x8*)(vh + (size_t)srow * NN + kt + BK + sc8);
            vr1 = *(const f16x8*)(vh + (size_t)srow2 * NN + kt + BK + sc82);
        }

        // S^T = K.Q^T per key-tile; each K-frag read feeds both q-strips
        f16x8 bf[2][2];
        #pragma unroll
        for (int t = 0; t < 4; ++t) {
            f16x8 a0 = *(const f16x8*)(&Ks[t * 16 + l16][quad * 8]);
            f16x8 a1 = *(const f16x8*)(&Ks[t * 16 + l16][32 + quad * 8]);
            #pragma unroll
            for (int s = 0; s < 2; ++s) {
                f32x4 st = {0.f, 0.f, 0.f, 0.f};
                st = __builtin_amdgcn_mfma_f32_16x16x32_f16(a0, qf[s][0], st, 0, 0, 0);
                st = __builtin_amdgcn_mfma_f32_16x16x32_f16(a1, qf[s][1], st, 0, 0, 0);
                float p0 = hexp2(st[0]);
                float p1 = hexp2(st[1]);
                float p2 = hexp2(st[2]);
                float p3 = hexp2(st[3]);
                lp[s] += (p0 + p1) + (p2 + p3);
                f16x8& b = bf[s][t >> 1];
                const int o = (t & 1) * 4;
                b[o + 0] = (f16)p0; b[o + 1] = (f16)p1;
                b[o + 2] = (f16)p2; b[o + 3] = (f16)p3;
            }
        }

        // O^T += V^T P^T ; each V-frag read feeds both strips
        #pragma unroll
        for (int te = 0; te < 4; ++te) {
            f16x8 v0 = *(const f16x8*)(&VsT[te * 16 + l16][quad * 8]);
            f16x8 v1 = *(const f16x8*)(&VsT[te * 16 + l16][32 + quad * 8]);
            #pragma unroll
            for (int s = 0; s < 2; ++s) {
                O[s][te] = __builtin_amdgcn_mfma_f32_16x16x32_f16(v0, bf[s][0], O[s][te], 0, 0, 0);
                O[s][te] = __builtin_amdgcn_mfma_f32_16x16x32_f16(v1, bf[s][1], O[s][te], 0, 0, 0);
            }
        }
    }

    // epilogue per strip: O^T C-layout: lane holds O^T[e=te*16+quad*4+r][qrow=l16]
    #pragma unroll
    for (int s = 0; s < 2; ++s) {
        float l = lp[s];
        l += __shfl_xor(l, 16);
        l += __shfl_xor(l, 32);
        const int row = n0 + s * 64 + m0 + l16;
        if (quad == 0)
            lpart[(size_t)sp * HH * NN + (size_t)h * NN + row] = l;
        float* obase = Opart + ((size_t)sp * NN + row) * DD + h * EE;
        #pragma unroll
        for (int te = 0; te < 4; ++te)
            *(f32x4*)(obase + te * 16 + quad * 4) = O[s][te];
    }
}

// ---------------- combine K-split partials: zh = sum(O_s)/sum(l_s), f16 out ----------------
__global__ __launch_bounds__(256) void attn_combine_kernel(
    const float* __restrict__ Opart, const float* __restrict__ lpart, f16* __restrict__ zh, int nsp)
{
    const size_t idx = ((size_t)blockIdx.x * 256 + threadIdx.x) * 8;
    const int n = (int)(idx >> 9);
    const int h = (int)((idx & 511) >> 6);
    float l = 0.f;
    for (int s = 0; s < nsp; ++s) l += lpart[(size_t)s * HH * NN + (size_t)h * NN + n];
    const float inv = 1.f / l;
    f32x4 a0 = {0.f,0.f,0.f,0.f}, a1 = {0.f,0.f,0.f,0.f};
    for (int s = 0; s < nsp; ++s) {
        a0 += *(const f32x4*)(Opart + (size_t)s * NN * DD + idx);
        a1 += *(const f32x4*)(Opart + (size_t)s * NN * DD + idx + 4);
    }
    f16x8 o;
    #pragma unroll
    for (int i = 0; i < 4; ++i) {
        o[i]     = (f16)(a0[i] * inv);
        o[i + 4] = (f16)(a1[i] * inv);
    }
    *(f16x8*)(zh + idx) = o;
}

// ---------------- GEMM via MFMA + bias/residual epilogue, fp32 out ----------------
__global__ __launch_bounds__(256) void gemm_mfma_kernel(
    const f16* __restrict__ A, const f16* __restrict__ BT,
    const float* __restrict__ bias, const float* __restrict__ resid32,
    const f16* __restrict__ resid16, float* __restrict__ out)
{
    __shared__ f16 As[64][72];
    __shared__ f16 Bs[64][72];
    const int tid = threadIdx.x;
    const int n0 = blockIdx.x * 64;
    const int j0 = blockIdx.y * 64;
    const f16* Arow = A + (size_t)n0 * DD;
    const f16* Brow = BT + (size_t)j0 * DD;

    const int lane = tid & 63, wave = tid >> 6;
    const int l16 = lane & 15, quad = lane >> 4;
    const int m0 = wave * 16;

    f32x4 acc[4];
    #pragma unroll
    for (int t = 0; t < 4; ++t) acc[t] = (f32x4){0.f, 0.f, 0.f, 0.f};

    for (int kt = 0; kt < DD; kt += 64) {
        __syncthreads();
        #pragma unroll
        for (int i = 0; i < 2; ++i) {
            int idx = tid + i * 256;
            int r = idx >> 3, c8 = (idx & 7) * 8;
            *(f16x8*)(&As[r][c8]) = *(const f16x8*)(Arow + (size_t)r * DD + kt + c8);
            *(f16x8*)(&Bs[r][c8]) = *(const f16x8*)(Brow + (size_t)r * DD + kt + c8);
        }
        __syncthreads();
        #pragma unroll
        for (int kk = 0; kk < 64; kk += 32) {
            f16x8 a = *(const f16x8*)(&As[m0 + l16][kk + quad * 8]);
            #pragma unroll
            for (int t = 0; t < 4; ++t) {
                f16x8 b = *(const f16x8*)(&Bs[t * 16 + l16][kk + quad * 8]);
                acc[t] = __builtin_amdgcn_mfma_f32_16x16x32_f16(a, b, acc[t], 0, 0, 0);
            }
        }
    }

    #pragma unroll
    for (int r = 0; r < 4; ++r) {
        int row = n0 + m0 + quad * 4 + r;
        #pragma unroll
        for (int t = 0; t < 4; ++t) {
            int col = j0 + t * 16 + l16;
            float v = acc[t][r];
            if (bias)    v += bias[col];
            if (resid32) v += resid32[(size_t)row * DD + col];
            if (resid16) v += (float)resid16[(size_t)row * DD + col];
            out[(size_t)row * DD + col] = v;
        }
    }
}

// ---------------- row LayerNorm: y fp32 [N][512] -> f16 and/or fp32 out ----------------
__global__ __launch_bounds__(256) void ln_kernel(
    const float* __restrict__ y, const float* __restrict__ g, const float* __restrict__ b,
    f16* __restrict__ oh, float* __restrict__ of)
{
    const int lane = threadIdx.x & 63, wave = threadIdx.x >> 6;
    const int row = blockIdx.x * 4 + wave;
    const float* yr = y + (size_t)row * DD;
    f32x4 v0 = *(const f32x4*)(yr + lane * 4);
    f32x4 v1 = *(const f32x4*)(yr + 256 + lane * 4);
    float s = (v0[0] + v0[1]) + (v0[2] + v0[3]) + (v1[0] + v1[1]) + (v1[2] + v1[3]);
    float q = (v0[0]*v0[0] + v0[1]*v0[1]) + (v0[2]*v0[2] + v0[3]*v0[3])
            + (v1[0]*v1[0] + v1[1]*v1[1]) + (v1[2]*v1[2] + v1[3]*v1[3]);
    #pragma unroll
    for (int o = 1; o < 64; o <<= 1) { s += __shfl_xor(s, o); q += __shfl_xor(q, o); }
    float mean = s * (1.f / DD);
    float var = q * (1.f / DD) - mean * mean;
    float inv = rsqrtf(var + 1e-5f);

    f32x4 g0 = *(const f32x4*)(g + lane * 4);
    f32x4 g1 = *(const f32x4*)(g + 256 + lane * 4);
    f32x4 b0 = *(const f32x4*)(b + lane * 4);
    f32x4 b1 = *(const f32x4*)(b + 256 + lane * 4);
    f32x4 o0, o1;
    #pragma unroll
    for (int i = 0; i < 4; ++i) {
        o0[i] = (v0[i] - mean) * inv * g0[i] + b0[i];
        o1[i] = (v1[i] - mean) * inv * g1[i] + b1[i];
    }
    if (oh) {
        f16x4 h0 = { (f16)o0[0], (f16)o0[1], (f16)o0[2], (f16)o0[3] };
        f16x4 h1 = { (f16)o1[0], (f16)o1[1], (f16)o1[2], (f16)o1[3] };
        *(f16x4*)(oh + (size_t)row * DD + lane * 4) = h0;
        *(f16x4*)(oh + (size_t)row * DD + 256 + lane * 4) = h1;
    }
    if (of) {
        *(f32x4*)(of + (size_t)row * DD + lane * 4) = o0;
        *(f32x4*)(of + (size_t)row * DD + 256 + lane * 4) = o1;
    }
}

extern "C" void kernel_launch(void* const* d_in, const int* in_sizes, int n_in,
                              void* d_out, int out_size, void* d_ws, size_t ws_size,
                              hipStream_t stream) {
    const float* x     = (const float*)d_in[0];
    const float* wq    = (const float*)d_in[1];
    const float* wk    = (const float*)d_in[2];
    const float* wv    = (const float*)d_in[3];
    const float* w_mh  = (const float*)d_in[4];
    const float* ln1_g = (const float*)d_in[5];
    const float* ln1_b = (const float*)d_in[6];
    const float* ffn_w = (const float*)d_in[7];
    const float* ffn_b = (const float*)d_in[8];
    const float* ln2_g = (const float*)d_in[9];
    const float* ln2_b = (const float*)d_in[10];
    float* out = (float*)d_out;

    // pool of f16 buffers that live across phases
    const size_t poolHalfs = (size_t)3 * HH * EE * DD + 2 * (size_t)DD * DD
                           + 3 * (size_t)HH * NN * EE + 2 * (size_t)NN * DD;
    // pick K-split count by available workspace (deterministic per session)
    int SP = 2;
    {
        size_t need4 = ((size_t)4 * NN * DD + 4 * HH * NN) * 4 + poolHalfs * 2 + 1024;
        size_t need3 = ((size_t)3 * NN * DD + 3 * HH * NN) * 4 + poolHalfs * 2 + 1024;
        if (ws_size >= need4) SP = 4; else if (ws_size >= need3) SP = 3;
    }

    // region A (aliased): xh (pre-attn) / Opart+lpart (attn) / y (post-combine)
    char* base = (char*)d_ws;
    float* Opart = (float*)base;                              // SP*NN*DD f32
    float* lpart = Opart + (size_t)SP * NN * DD;              // SP*HH*NN f32
    f16* xh   = (f16*)base;                                   // alias (pre-attention)
    float* y  = (float*)base;                                 // alias (post-combine)
    size_t regionA = ((size_t)SP * NN * DD + (size_t)SP * HH * NN) * sizeof(float);
    regionA = (regionA + 255) & ~(size_t)255;
    f16* p = (f16*)(base + regionA);
    f16* wqkvT  = p; p += (size_t)3 * HH * EE * DD;           // [sel][h][e][d]
    f16* wmhT   = p; p += (size_t)DD * DD;                    // [j][k]
    f16* ffnT   = p; p += (size_t)DD * DD;                    // [j][k]
    f16* qh     = p; p += (size_t)HH * NN * EE;               // [h][n][e], scale baked
    f16* kh     = p; p += (size_t)HH * NN * EE;               // [h][n][e]
    f16* vTh    = p; p += (size_t)HH * NN * EE;               // [h][e][n]
    f16* zh     = p; p += (size_t)NN * DD;                    // [n][h*e]
    f16* nzh    = p; p += (size_t)NN * DD;                    // LN1 out

    // prep (single launch)
    prep_kernel<<<dim3(256, 6), 256, 0, stream>>>(x, ffn_w, wq, wk, wv, w_mh,
                                                  xh, ffnT, wqkvT, wmhT);

    // main chain
    qkv_mfma_kernel<<<dim3(NN / 64, 24), 256, 0, stream>>>(xh, wqkvT, qh, kh, vTh);
    attn_mfma_kernel<<<dim3(NN / BQ, HH, SP), 256, 0, stream>>>(qh, kh, vTh, Opart, lpart);
    attn_combine_kernel<<<dim3(NN * DD / 2048), 256, 0, stream>>>(Opart, lpart, zh, SP);
    gemm_mfma_kernel<<<dim3(NN / 64, DD / 64), 256, 0, stream>>>(zh, wmhT, nullptr, x, nullptr, y);
    ln_kernel<<<dim3(NN / 4), 256, 0, stream>>>(y, ln1_g, ln1_b, nzh, nullptr);
    gemm_mfma_kernel<<<dim3(NN / 64, DD / 64), 256, 0, stream>>>(nzh, ffnT, ffn_b, nullptr, nzh, y);
    ln_kernel<<<dim3(NN / 4), 256, 0, stream>>>(y, ln2_g, ln2_b, nullptr, out);
}